// Round 10
// baseline (823.224 us; speedup 1.0000x reference)
//
#include <hip/hip_runtime.h>
#include <math.h>

#define TT   512
#define BB   512
#define DIN  64
#define DLAT 128
#define KKK  192                 // DLAT + DIN
#define NBLK 32                  // xproj batch blocks (16 rows each)
#define NBLK_R 16                // recurrent blocks (32 rows each, 2 groups)
#define TCHUNK 16
#define X_ELEMS ((size_t)TT * BB * 384)
#define X_BYTES (X_ELEMS * 2)    // 201 MB f16

typedef _Float16 half8 __attribute__((ext_vector_type(8)));
typedef _Float16 half4 __attribute__((ext_vector_type(4)));
typedef float    f32x4 __attribute__((ext_vector_type(4)));

#define MFMA16(A, B, C) __builtin_amdgcn_mfma_f32_16x16x32_f16((A), (B), (C), 0, 0, 0)

__device__ __forceinline__ float fsigmoid(float x) {
    float e = __builtin_amdgcn_exp2f(-1.44269504f * x);
    return __builtin_amdgcn_rcpf(1.f + e);
}
__device__ __forceinline__ float ftanh(float x) {
    float e = __builtin_amdgcn_exp2f(2.88539008f * x);
    return 1.f - 2.f * __builtin_amdgcn_rcpf(1.f + e);
}
__device__ __forceinline__ half8 cvt8(float4 a, float4 b) {
    return (half8){(_Float16)a.x, (_Float16)a.y, (_Float16)a.z, (_Float16)a.w,
                   (_Float16)b.x, (_Float16)b.y, (_Float16)b.z, (_Float16)b.w};
}

// Group-local barrier (4 waves): release-add + acquire-poll on an LDS
// counter. Decouples the two co-resident groups so their pipeline phases
// interleave on each SIMD instead of lock-stepping via s_barrier.
__device__ __forceinline__ void gbar(unsigned* cnt, unsigned target, int lane) {
    asm volatile("s_waitcnt lgkmcnt(0)" ::: "memory");  // drain this wave's LDS writes
    if (lane == 0)
        __hip_atomic_fetch_add(cnt, 1u, __ATOMIC_RELEASE, __HIP_MEMORY_SCOPE_WORKGROUP);
    while (__hip_atomic_load(cnt, __ATOMIC_ACQUIRE, __HIP_MEMORY_SCOPE_WORKGROUP) < target)
        __builtin_amdgcn_s_sleep(1);
}

// ============ Kernel 1: parallel x-projection GEMM (all 256 CUs) ============
// (unchanged from R8/R9)
__global__ __launch_bounds__(256) void xproj(
    const float* __restrict__ seqs,
    const float* __restrict__ Wz, const float* __restrict__ bz,
    const float* __restrict__ Wr, const float* __restrict__ br,
    const float* __restrict__ Wi, const float* __restrict__ bi,
    _Float16* __restrict__ X)
{
    const int tid = threadIdx.x;
    const int w = tid >> 6, l = tid & 63, q = l >> 4, ln = l & 15;
    const int bid = blockIdx.x;
    const int tb  = bid >> 5;          // t-chunk 0..31
    const int blk = bid & 31;
    const int b0  = blk * 16;

    half8 wzf[2][2], wrf[2][2], wif[2][2];
    float bzv[2], brv[2], biv[2];
    #pragma unroll
    for (int s = 0; s < 2; ++s) {
        const int n = 32 * w + 16 * s + ln;
        #pragma unroll
        for (int kt = 0; kt < 2; ++kt) {
            const int k0 = DLAT + kt * 32 + q * 8;
            wzf[s][kt] = cvt8(*(const float4*)&Wz[n * KKK + k0],
                              *(const float4*)&Wz[n * KKK + k0 + 4]);
            wrf[s][kt] = cvt8(*(const float4*)&Wr[n * KKK + k0],
                              *(const float4*)&Wr[n * KKK + k0 + 4]);
            wif[s][kt] = cvt8(*(const float4*)&Wi[n * KKK + k0],
                              *(const float4*)&Wi[n * KKK + k0 + 4]);
        }
        bzv[s] = bz[n]; brv[s] = br[n]; biv[s] = bi[n];
    }

    for (int tt = 0; tt < TCHUNK; ++tt) {
        const int t = tb * TCHUNK + tt;
        const float* xr = seqs + ((size_t)t * BB + b0 + ln) * DIN + q * 8;
        half8 a0 = cvt8(*(const float4*)xr,        *(const float4*)(xr + 4));
        half8 a1 = cvt8(*(const float4*)(xr + 32), *(const float4*)(xr + 36));

        f32x4 az[2], ar[2], ai[2];
        #pragma unroll
        for (int s = 0; s < 2; ++s) {
            az[s] = (f32x4){bzv[s], bzv[s], bzv[s], bzv[s]};
            ar[s] = (f32x4){brv[s], brv[s], brv[s], brv[s]};
            ai[s] = (f32x4){biv[s], biv[s], biv[s], biv[s]};
        }
        #pragma unroll
        for (int s = 0; s < 2; ++s) {
            az[s] = MFMA16(a0, wzf[s][0], az[s]);
            az[s] = MFMA16(a1, wzf[s][1], az[s]);
            ar[s] = MFMA16(a0, wrf[s][0], ar[s]);
            ar[s] = MFMA16(a1, wrf[s][1], ar[s]);
            ai[s] = MFMA16(a0, wif[s][0], ai[s]);
            ai[s] = MFMA16(a1, wif[s][1], ai[s]);
        }

        half8 o0, o1, o2;
        #pragma unroll
        for (int s = 0; s < 2; ++s)
            #pragma unroll
            for (int i = 0; i < 4; ++i) {
                o0[s * 4 + i] = (_Float16)az[s][i];
                o1[s * 4 + i] = (_Float16)ar[s][i];
                o2[s * 4 + i] = (_Float16)ai[s][i];
            }
        _Float16* xo = X + ((size_t)(t * NBLK + blk) * 256 + tid) * 24;
        *(half8*)xo        = o0;
        *(half8*)(xo +  8) = o1;
        *(half8*)(xo + 16) = o2;
    }
}

// ============ Kernel 2: persistent recurrence, 2 DECOUPLED groups ============
// 16 blocks x 512 threads (8 waves = 2/SIMD). Waves 0-3 = group 0, waves 4-7
// = group 1; groups fully independent (separate hA/hrA/h/counters) and sync
// ONLY within their group via LDS spin barriers — no workgroup s_barrier in
// the loop, so the two waves on each SIMD interleave freely.
__global__ __launch_bounds__(512, 2) void gru_rx(
    const float* __restrict__ h0,
    const float* __restrict__ Wz, const float* __restrict__ Wr,
    const float* __restrict__ Wi,
    const _Float16* __restrict__ X, float* __restrict__ out)
{
    __shared__ __align__(16) _Float16 hA [2][16][136];
    __shared__ __align__(16) _Float16 hrA[2][16][136];
    __shared__ unsigned gcnt[2];

    const int tid = threadIdx.x;
    const int w   = tid >> 6;          // wave 0..7
    const int grp = w >> 2;            // group 0..1
    const int wl  = w & 3;             // wave within group
    const int l   = tid & 63;
    const int q   = l >> 4;
    const int ln  = l & 15;
    const int blk = (int)blockIdx.x;
    const int b0g = blk * 32 + grp * 16;           // group's first batch row
    const int xblk = blk * 2 + grp;                // xproj block id
    const int gtid = wl * 64 + l;                  // tid within group (0..255)

    if (tid < 2) gcnt[tid] = 0;

    // h-part weight frags (cols 0..128) for this wave's gate columns
    half8 wzf[2][4], wrf[2][4], wif[2][4];
    #pragma unroll
    for (int s = 0; s < 2; ++s) {
        const int n = 32 * wl + 16 * s + ln;
        #pragma unroll
        for (int kt = 0; kt < 4; ++kt) {
            const int k0 = kt * 32 + q * 8;
            wzf[s][kt] = cvt8(*(const float4*)&Wz[n * KKK + k0],
                              *(const float4*)&Wz[n * KKK + k0 + 4]);
            wrf[s][kt] = cvt8(*(const float4*)&Wr[n * KKK + k0],
                              *(const float4*)&Wr[n * KKK + k0 + 4]);
            wif[s][kt] = cvt8(*(const float4*)&Wi[n * KKK + k0],
                              *(const float4*)&Wi[n * KKK + k0 + 4]);
        }
    }

    // h state in registers (C-layout slots) + hA + out[0]
    float h[2][4];
    #pragma unroll
    for (int s = 0; s < 2; ++s)
        #pragma unroll
        for (int i = 0; i < 4; ++i)
            h[s][i] = h0[(size_t)(b0g + 4 * q + i) * DLAT + 32 * wl + 16 * s + ln];

    for (int idx = gtid; idx < 16 * DLAT; idx += 256) {
        const int m = idx >> 7, c = idx & 127;
        const float v = h0[(size_t)(b0g + m) * DLAT + c];
        out[(size_t)(b0g + m) * DLAT + c] = v;
        hA[grp][m][c] = (_Float16)v;
    }

    // X[0] for this thread (gate-major: z, r, i)
    half8 xc0, xc1, xc2;
    {
        const _Float16* xp = X + ((size_t)(0 * NBLK + xblk) * 256 + gtid) * 24;
        xc0 = *(const half8*)xp;
        xc1 = *(const half8*)(xp + 8);
        xc2 = *(const half8*)(xp + 16);
    }
    __syncthreads();   // one-time: gcnt + hA init visible

    unsigned tgt = 4;  // group barrier target (4 waves per group)

    for (int t = 0; t < TT; ++t) {
        // prefetch X[t+1]
        half8 xn0, xn1, xn2;
        const bool have = (t + 1 < TT);
        if (have) {
            const _Float16* xp = X + ((size_t)((t + 1) * NBLK + xblk) * 256 + gtid) * 24;
            xn0 = *(const half8*)xp;
            xn1 = *(const half8*)(xp + 8);
            xn2 = *(const half8*)(xp + 16);
        }

        half8 a0 = *(const half8*)&hA[grp][ln][ 0 + q * 8];
        half8 a1 = *(const half8*)&hA[grp][ln][32 + q * 8];
        half8 a2 = *(const half8*)&hA[grp][ln][64 + q * 8];
        half8 a3 = *(const half8*)&hA[grp][ln][96 + q * 8];

        // ---- phase 1: r chain then z chain; r-sigmoid overlaps z MFMAs
        f32x4 ar[2], az[2], ai[2];
        #pragma unroll
        for (int s = 0; s < 2; ++s)
            #pragma unroll
            for (int i = 0; i < 4; ++i) {
                ar[s][i] = (float)xc1[s * 4 + i];
                az[s][i] = (float)xc0[s * 4 + i];
            }
        #pragma unroll
        for (int s = 0; s < 2; ++s) {
            ar[s] = MFMA16(a0, wrf[s][0], ar[s]);
            ar[s] = MFMA16(a1, wrf[s][1], ar[s]);
            ar[s] = MFMA16(a2, wrf[s][2], ar[s]);
            ar[s] = MFMA16(a3, wrf[s][3], ar[s]);
        }
        #pragma unroll
        for (int s = 0; s < 2; ++s) {
            az[s] = MFMA16(a0, wzf[s][0], az[s]);
            az[s] = MFMA16(a1, wzf[s][1], az[s]);
            az[s] = MFMA16(a2, wzf[s][2], az[s]);
            az[s] = MFMA16(a3, wzf[s][3], az[s]);
        }
        #pragma unroll
        for (int s = 0; s < 2; ++s)
            #pragma unroll
            for (int i = 0; i < 4; ++i) {
                const float r = fsigmoid(ar[s][i]);
                hrA[grp][4 * q + i][32 * wl + 16 * s + ln] = (_Float16)(h[s][i] * r);
            }

        gbar(&gcnt[grp], tgt, l); tgt += 4;   // group-local: hr visible

        // ---- phase 2: cand chain; z-sigmoid overlaps cand MFMAs
        half8 c0 = *(const half8*)&hrA[grp][ln][ 0 + q * 8];
        half8 c1 = *(const half8*)&hrA[grp][ln][32 + q * 8];
        half8 c2 = *(const half8*)&hrA[grp][ln][64 + q * 8];
        half8 c3 = *(const half8*)&hrA[grp][ln][96 + q * 8];
        #pragma unroll
        for (int s = 0; s < 2; ++s)
            #pragma unroll
            for (int i = 0; i < 4; ++i)
                ai[s][i] = (float)xc2[s * 4 + i];
        #pragma unroll
        for (int s = 0; s < 2; ++s) {
            ai[s] = MFMA16(c0, wif[s][0], ai[s]);
            ai[s] = MFMA16(c1, wif[s][1], ai[s]);
            ai[s] = MFMA16(c2, wif[s][2], ai[s]);
            ai[s] = MFMA16(c3, wif[s][3], ai[s]);
        }
        float zz[2][4];
        #pragma unroll
        for (int s = 0; s < 2; ++s)
            #pragma unroll
            for (int i = 0; i < 4; ++i)
                zz[s][i] = fsigmoid(az[s][i]);

        #pragma unroll
        for (int s = 0; s < 2; ++s)
            #pragma unroll
            for (int i = 0; i < 4; ++i) {
                const float cand = ftanh(ai[s][i]);
                const float hn   = h[s][i] + zz[s][i] * (cand - h[s][i]);
                h[s][i] = hn;
                const int m = 4 * q + i, c = 32 * wl + 16 * s + ln;
                hA[grp][m][c] = (_Float16)hn;
                out[((size_t)(t + 1) * BB + b0g + m) * DLAT + c] = hn;
            }

        xc0 = xn0; xc1 = xn1; xc2 = xn2;
        gbar(&gcnt[grp], tgt, l); tgt += 4;   // group-local: new h visible
    }
}

// ============ Fallback (R6 kernel, verbatim): used if ws too small ============
__global__ __launch_bounds__(256, 1) void gru_mfma(
    const float* __restrict__ seqs, const float* __restrict__ h0,
    const float* __restrict__ bz, const float* __restrict__ br,
    const float* __restrict__ bi,
    const float* __restrict__ Wz, const float* __restrict__ Wr,
    const float* __restrict__ Wi, float* __restrict__ out)
{
    __shared__ __align__(16) _Float16 hA [16][136];
    __shared__ __align__(16) _Float16 hrA[16][136];
    __shared__ __align__(16) _Float16 xb [2][16][72];

    const int tid = threadIdx.x;
    const int w   = tid >> 6;
    const int l   = tid & 63;
    const int q   = l >> 4;
    const int ln  = l & 15;
    const int b0  = (int)blockIdx.x * 16;

    half8 wz[2][6], wr[2][6], wi[2][6];
    #pragma unroll
    for (int s = 0; s < 2; ++s) {
        const int n = 32 * w + 16 * s + ln;
        #pragma unroll
        for (int kt = 0; kt < 6; ++kt) {
            const int k0 = kt * 32 + q * 8;
            wz[s][kt] = cvt8(*(const float4*)&Wz[n * KKK + k0],
                             *(const float4*)&Wz[n * KKK + k0 + 4]);
            wr[s][kt] = cvt8(*(const float4*)&Wr[n * KKK + k0],
                             *(const float4*)&Wr[n * KKK + k0 + 4]);
            wi[s][kt] = cvt8(*(const float4*)&Wi[n * KKK + k0],
                             *(const float4*)&Wi[n * KKK + k0 + 4]);
        }
    }
    float bzv[2], brv[2], biv[2];
    #pragma unroll
    for (int s = 0; s < 2; ++s) {
        const int n = 32 * w + 16 * s + ln;
        bzv[s] = bz[n]; brv[s] = br[n]; biv[s] = bi[n];
    }

    float h[2][4];
    #pragma unroll
    for (int s = 0; s < 2; ++s)
        #pragma unroll
        for (int i = 0; i < 4; ++i)
            h[s][i] = h0[(size_t)(b0 + 4 * q + i) * DLAT + 32 * w + 16 * s + ln];

    for (int idx = tid; idx < 16 * DLAT; idx += 256) {
        const int m = idx >> 7, c = idx & 127;
        const float v = h0[(size_t)(b0 + m) * DLAT + c];
        out[(size_t)(b0 + m) * DLAT + c] = v;
        hA[m][c] = (_Float16)v;
    }
    {
        const int m = tid >> 4, k4 = tid & 15;
        const float4 xv = *(const float4*)&seqs[((size_t)0 * BB + b0 + m) * DIN + k4 * 4];
        *(half4*)&xb[0][m][k4 * 4] =
            (half4){(_Float16)xv.x, (_Float16)xv.y, (_Float16)xv.z, (_Float16)xv.w};
    }
    __syncthreads();

    for (int t = 0; t < TT; ++t) {
        const int p = t & 1;
        float4 xv;
        const int xm = tid >> 4, xk = tid & 15;
        if (t + 1 < TT)
            xv = *(const float4*)&seqs[((size_t)(t + 1) * BB + b0 + xm) * DIN + xk * 4];

        half8 a0 = *(const half8*)&hA[ln][ 0 + q * 8];
        half8 a1 = *(const half8*)&hA[ln][32 + q * 8];
        half8 a2 = *(const half8*)&hA[ln][64 + q * 8];
        half8 a3 = *(const half8*)&hA[ln][96 + q * 8];
        half8 x0 = *(const half8*)&xb[p][ln][ 0 + q * 8];
        half8 x1 = *(const half8*)&xb[p][ln][32 + q * 8];

        f32x4 az[2], ar[2], ai[2];
        #pragma unroll
        for (int s = 0; s < 2; ++s) {
            az[s] = (f32x4){bzv[s], bzv[s], bzv[s], bzv[s]};
            ar[s] = (f32x4){brv[s], brv[s], brv[s], brv[s]};
            ai[s] = (f32x4){biv[s], biv[s], biv[s], biv[s]};
        }
        #pragma unroll
        for (int s = 0; s < 2; ++s) {
            az[s] = MFMA16(x0, wz[s][4], az[s]);
            az[s] = MFMA16(x1, wz[s][5], az[s]);
            ar[s] = MFMA16(x0, wr[s][4], ar[s]);
            ar[s] = MFMA16(x1, wr[s][5], ar[s]);
            ai[s] = MFMA16(x0, wi[s][4], ai[s]);
            ai[s] = MFMA16(x1, wi[s][5], ai[s]);
            az[s] = MFMA16(a0, wz[s][0], az[s]);
            az[s] = MFMA16(a1, wz[s][1], az[s]);
            az[s] = MFMA16(a2, wz[s][2], az[s]);
            az[s] = MFMA16(a3, wz[s][3], az[s]);
            ar[s] = MFMA16(a0, wr[s][0], ar[s]);
            ar[s] = MFMA16(a1, wr[s][1], ar[s]);
            ar[s] = MFMA16(a2, wr[s][2], ar[s]);
            ar[s] = MFMA16(a3, wr[s][3], ar[s]);
        }

        float zz[2][4];
        #pragma unroll
        for (int s = 0; s < 2; ++s)
            #pragma unroll
            for (int i = 0; i < 4; ++i) {
                zz[s][i]      = fsigmoid(az[s][i]);
                const float r = fsigmoid(ar[s][i]);
                hrA[4 * q + i][32 * w + 16 * s + ln] = (_Float16)(h[s][i] * r);
            }

        if (t + 1 < TT)
            *(half4*)&xb[p ^ 1][xm][xk * 4] =
                (half4){(_Float16)xv.x, (_Float16)xv.y, (_Float16)xv.z, (_Float16)xv.w};

        __syncthreads();

        half8 c0 = *(const half8*)&hrA[ln][ 0 + q * 8];
        half8 c1 = *(const half8*)&hrA[ln][32 + q * 8];
        half8 c2 = *(const half8*)&hrA[ln][64 + q * 8];
        half8 c3 = *(const half8*)&hrA[ln][96 + q * 8];
        #pragma unroll
        for (int s = 0; s < 2; ++s) {
            ai[s] = MFMA16(c0, wi[s][0], ai[s]);
            ai[s] = MFMA16(c1, wi[s][1], ai[s]);
            ai[s] = MFMA16(c2, wi[s][2], ai[s]);
            ai[s] = MFMA16(c3, wi[s][3], ai[s]);
        }

        #pragma unroll
        for (int s = 0; s < 2; ++s)
            #pragma unroll
            for (int i = 0; i < 4; ++i) {
                const float cand = ftanh(ai[s][i]);
                const float hn   = h[s][i] + zz[s][i] * (cand - h[s][i]);
                h[s][i] = hn;
                const int m = 4 * q + i, c = 32 * w + 16 * s + ln;
                hA[m][c] = (_Float16)hn;
                out[((size_t)(t + 1) * BB + b0 + m) * DLAT + c] = hn;
            }

        __syncthreads();
    }
}

extern "C" void kernel_launch(void* const* d_in, const int* in_sizes, int n_in,
                              void* d_out, int out_size, void* d_ws, size_t ws_size,
                              hipStream_t stream) {
    const float* seqs = (const float*)d_in[0];
    const float* h0   = (const float*)d_in[1];
    const float* Wz   = (const float*)d_in[2];
    const float* bz   = (const float*)d_in[3];
    const float* Wr   = (const float*)d_in[4];
    const float* br   = (const float*)d_in[5];
    const float* Wi   = (const float*)d_in[6];
    const float* bi   = (const float*)d_in[7];
    float* out = (float*)d_out;

    if (ws_size >= X_BYTES) {
        _Float16* X = (_Float16*)d_ws;
        xproj<<<(TT / TCHUNK) * NBLK, 256, 0, stream>>>(seqs, Wz, bz, Wr, br, Wi, bi, X);
        gru_rx<<<NBLK_R, 512, 0, stream>>>(h0, Wz, Wr, Wi, X, out);
    } else {
        gru_mfma<<<NBLK, 256, 0, stream>>>(seqs, h0, bz, br, bi, Wz, Wr, Wi, out);
    }
}

// Round 11
// 508.579 us; speedup vs baseline: 1.6187x; 1.6187x over previous
//
#include <hip/hip_runtime.h>
#include <math.h>

#define TT   512
#define BB   512
#define DIN  64
#define DLAT 128
#define KKK  192                 // DLAT + DIN
#define NBLK 32                  // xproj batch blocks (16 rows each)
#define TCHUNK 16
#define X_ELEMS ((size_t)TT * BB * 384)
#define X_BYTES (X_ELEMS * 2)    // 201 MB f16

typedef _Float16 half8 __attribute__((ext_vector_type(8)));
typedef _Float16 half4 __attribute__((ext_vector_type(4)));
typedef float    f32x4 __attribute__((ext_vector_type(4)));

#define MFMA16(A, B, C) __builtin_amdgcn_mfma_f32_16x16x32_f16((A), (B), (C), 0, 0, 0)

__device__ __forceinline__ float fsigmoid(float x) {
    float e = __builtin_amdgcn_exp2f(-1.44269504f * x);
    return __builtin_amdgcn_rcpf(1.f + e);
}
__device__ __forceinline__ float ftanh(float x) {
    float e = __builtin_amdgcn_exp2f(2.88539008f * x);
    return 1.f - 2.f * __builtin_amdgcn_rcpf(1.f + e);
}
__device__ __forceinline__ half8 cvt8(float4 a, float4 b) {
    return (half8){(_Float16)a.x, (_Float16)a.y, (_Float16)a.z, (_Float16)a.w,
                   (_Float16)b.x, (_Float16)b.y, (_Float16)b.z, (_Float16)b.w};
}

// ============ Kernel 1: parallel x-projection GEMM (all 256 CUs) ============
// (unchanged from R8)
__global__ __launch_bounds__(256) void xproj(
    const float* __restrict__ seqs,
    const float* __restrict__ Wz, const float* __restrict__ bz,
    const float* __restrict__ Wr, const float* __restrict__ br,
    const float* __restrict__ Wi, const float* __restrict__ bi,
    _Float16* __restrict__ X)
{
    const int tid = threadIdx.x;
    const int w = tid >> 6, l = tid & 63, q = l >> 4, ln = l & 15;
    const int bid = blockIdx.x;
    const int tb  = bid >> 5;          // t-chunk 0..31
    const int blk = bid & 31;
    const int b0  = blk * 16;

    half8 wzf[2][2], wrf[2][2], wif[2][2];
    float bzv[2], brv[2], biv[2];
    #pragma unroll
    for (int s = 0; s < 2; ++s) {
        const int n = 32 * w + 16 * s + ln;
        #pragma unroll
        for (int kt = 0; kt < 2; ++kt) {
            const int k0 = DLAT + kt * 32 + q * 8;
            wzf[s][kt] = cvt8(*(const float4*)&Wz[n * KKK + k0],
                              *(const float4*)&Wz[n * KKK + k0 + 4]);
            wrf[s][kt] = cvt8(*(const float4*)&Wr[n * KKK + k0],
                              *(const float4*)&Wr[n * KKK + k0 + 4]);
            wif[s][kt] = cvt8(*(const float4*)&Wi[n * KKK + k0],
                              *(const float4*)&Wi[n * KKK + k0 + 4]);
        }
        bzv[s] = bz[n]; brv[s] = br[n]; biv[s] = bi[n];
    }

    for (int tt = 0; tt < TCHUNK; ++tt) {
        const int t = tb * TCHUNK + tt;
        const float* xr = seqs + ((size_t)t * BB + b0 + ln) * DIN + q * 8;
        half8 a0 = cvt8(*(const float4*)xr,        *(const float4*)(xr + 4));
        half8 a1 = cvt8(*(const float4*)(xr + 32), *(const float4*)(xr + 36));

        f32x4 az[2], ar[2], ai[2];
        #pragma unroll
        for (int s = 0; s < 2; ++s) {
            az[s] = (f32x4){bzv[s], bzv[s], bzv[s], bzv[s]};
            ar[s] = (f32x4){brv[s], brv[s], brv[s], brv[s]};
            ai[s] = (f32x4){biv[s], biv[s], biv[s], biv[s]};
        }
        #pragma unroll
        for (int s = 0; s < 2; ++s) {
            az[s] = MFMA16(a0, wzf[s][0], az[s]);
            az[s] = MFMA16(a1, wzf[s][1], az[s]);
            ar[s] = MFMA16(a0, wrf[s][0], ar[s]);
            ar[s] = MFMA16(a1, wrf[s][1], ar[s]);
            ai[s] = MFMA16(a0, wif[s][0], ai[s]);
            ai[s] = MFMA16(a1, wif[s][1], ai[s]);
        }

        half8 o0, o1, o2;
        #pragma unroll
        for (int s = 0; s < 2; ++s)
            #pragma unroll
            for (int i = 0; i < 4; ++i) {
                o0[s * 4 + i] = (_Float16)az[s][i];
                o1[s * 4 + i] = (_Float16)ar[s][i];
                o2[s * 4 + i] = (_Float16)ai[s][i];
            }
        _Float16* xo = X + ((size_t)(t * NBLK + blk) * 256 + tid) * 24;
        *(half8*)xo        = o0;
        *(half8*)(xo +  8) = o1;
        *(half8*)(xo + 16) = o2;
    }
}

// ============ Kernel 2: persistent recurrence, 8 waves / 16-row group ============
// 32 blocks x 512 threads (8 waves = 2/SIMD), ALL waves on one 16-row group.
// Wave w owns gate cols [16w,16w+16) for z, r, cand: per-wave trans issue
// halves vs the 4-wave layout; the two waves on each SIMD serialize only on
// the shared trans unit and overlap MFMA/LDS/stall phases (R9 measured ~70%
// overlap efficiency for co-resident waves).
__global__ __launch_bounds__(512, 2) void gru_rx(
    const float* __restrict__ h0,
    const float* __restrict__ Wz, const float* __restrict__ Wr,
    const float* __restrict__ Wi,
    const _Float16* __restrict__ X, float* __restrict__ out)
{
    __shared__ __align__(16) _Float16 hA [16][136];
    __shared__ __align__(16) _Float16 hrA[16][136];

    const int tid = threadIdx.x;
    const int w   = tid >> 6;          // wave 0..7
    const int l   = tid & 63;
    const int q   = l >> 4;
    const int ln  = l & 15;
    const int blk = (int)blockIdx.x;
    const int b0  = blk * 16;
    const int nc  = 16 * w + ln;       // this thread's gate column

    // h-part weight frags (cols 0..128) for this wave's 16 columns
    half8 wzf[4], wrf[4], wif[4];
    #pragma unroll
    for (int kt = 0; kt < 4; ++kt) {
        const int k0 = kt * 32 + q * 8;
        wzf[kt] = cvt8(*(const float4*)&Wz[nc * KKK + k0],
                       *(const float4*)&Wz[nc * KKK + k0 + 4]);
        wrf[kt] = cvt8(*(const float4*)&Wr[nc * KKK + k0],
                       *(const float4*)&Wr[nc * KKK + k0 + 4]);
        wif[kt] = cvt8(*(const float4*)&Wi[nc * KKK + k0],
                       *(const float4*)&Wi[nc * KKK + k0 + 4]);
    }

    // h state in registers (C-layout slots: rows 4q+i, col nc) + hA + out[0]
    float h[4];
    #pragma unroll
    for (int i = 0; i < 4; ++i)
        h[i] = h0[(size_t)(b0 + 4 * q + i) * DLAT + nc];

    for (int idx = tid; idx < 16 * DLAT; idx += 512) {
        const int m = idx >> 7, c = idx & 127;
        const float v = h0[(size_t)(b0 + m) * DLAT + c];
        out[(size_t)(b0 + m) * DLAT + c] = v;
        hA[m][c] = (_Float16)v;
    }

    // X readback mapping (xproj layout is keyed to the 4-wave producer):
    // col nc -> producer w4 = w>>1, s = w&1; slot tid_x = (w>>1)*64 + q*16 + ln;
    // per-gate 4 halves at offset gate*8 + (w&1)*4.
    const size_t xslot = (size_t)((w >> 1) * 64 + q * 16 + ln) * 24 + (w & 1) * 4;

    half4 xc0, xc1, xc2;
    {
        const _Float16* xp = X + ((size_t)(0 * NBLK + blk) * 256) * 24 + xslot;
        xc0 = *(const half4*)xp;
        xc1 = *(const half4*)(xp + 8);
        xc2 = *(const half4*)(xp + 16);
    }
    __syncthreads();

    for (int t = 0; t < TT; ++t) {
        // prefetch X[t+1] (consumed next step)
        half4 xn0, xn1, xn2;
        const bool have = (t + 1 < TT);
        if (have) {
            const _Float16* xp = X + ((size_t)((t + 1) * NBLK + blk) * 256) * 24 + xslot;
            xn0 = *(const half4*)xp;
            xn1 = *(const half4*)(xp + 8);
            xn2 = *(const half4*)(xp + 16);
        }

        half8 a0 = *(const half8*)&hA[ln][ 0 + q * 8];
        half8 a1 = *(const half8*)&hA[ln][32 + q * 8];
        half8 a2 = *(const half8*)&hA[ln][64 + q * 8];
        half8 a3 = *(const half8*)&hA[ln][96 + q * 8];

        // ---- phase 1: r chain then z chain; r-sigmoid overlaps z MFMAs
        f32x4 ar, az, ai;
        #pragma unroll
        for (int i = 0; i < 4; ++i) {
            ar[i] = (float)xc1[i];
            az[i] = (float)xc0[i];
        }
        ar = MFMA16(a0, wrf[0], ar);
        ar = MFMA16(a1, wrf[1], ar);
        ar = MFMA16(a2, wrf[2], ar);
        ar = MFMA16(a3, wrf[3], ar);
        az = MFMA16(a0, wzf[0], az);
        az = MFMA16(a1, wzf[1], az);
        az = MFMA16(a2, wzf[2], az);
        az = MFMA16(a3, wzf[3], az);
        #pragma unroll
        for (int i = 0; i < 4; ++i) {
            const float r = fsigmoid(ar[i]);
            hrA[4 * q + i][nc] = (_Float16)(h[i] * r);
        }

        __syncthreads();   // hr visible (z-sigmoid deferred past barrier)

        // ---- phase 2: cand chain; z-sigmoid overlaps cand MFMAs
        half8 c0 = *(const half8*)&hrA[ln][ 0 + q * 8];
        half8 c1 = *(const half8*)&hrA[ln][32 + q * 8];
        half8 c2 = *(const half8*)&hrA[ln][64 + q * 8];
        half8 c3 = *(const half8*)&hrA[ln][96 + q * 8];
        #pragma unroll
        for (int i = 0; i < 4; ++i)
            ai[i] = (float)xc2[i];
        ai = MFMA16(c0, wif[0], ai);
        ai = MFMA16(c1, wif[1], ai);
        ai = MFMA16(c2, wif[2], ai);
        ai = MFMA16(c3, wif[3], ai);

        float zz[4];
        #pragma unroll
        for (int i = 0; i < 4; ++i)
            zz[i] = fsigmoid(az[i]);

        #pragma unroll
        for (int i = 0; i < 4; ++i) {
            const float cand = ftanh(ai[i]);
            const float hn   = h[i] + zz[i] * (cand - h[i]);
            h[i] = hn;
            hA[4 * q + i][nc] = (_Float16)hn;
            out[((size_t)(t + 1) * BB + b0 + 4 * q + i) * DLAT + nc] = hn;
        }

        xc0 = xn0; xc1 = xn1; xc2 = xn2;
        __syncthreads();   // new h visible for next step
    }
}

// ============ Fallback (R6 kernel, verbatim): used if ws too small ============
__global__ __launch_bounds__(256, 1) void gru_mfma(
    const float* __restrict__ seqs, const float* __restrict__ h0,
    const float* __restrict__ bz, const float* __restrict__ br,
    const float* __restrict__ bi,
    const float* __restrict__ Wz, const float* __restrict__ Wr,
    const float* __restrict__ Wi, float* __restrict__ out)
{
    __shared__ __align__(16) _Float16 hA [16][136];
    __shared__ __align__(16) _Float16 hrA[16][136];
    __shared__ __align__(16) _Float16 xb [2][16][72];

    const int tid = threadIdx.x;
    const int w   = tid >> 6;
    const int l   = tid & 63;
    const int q   = l >> 4;
    const int ln  = l & 15;
    const int b0  = (int)blockIdx.x * 16;

    half8 wz[2][6], wr[2][6], wi[2][6];
    #pragma unroll
    for (int s = 0; s < 2; ++s) {
        const int n = 32 * w + 16 * s + ln;
        #pragma unroll
        for (int kt = 0; kt < 6; ++kt) {
            const int k0 = kt * 32 + q * 8;
            wz[s][kt] = cvt8(*(const float4*)&Wz[n * KKK + k0],
                             *(const float4*)&Wz[n * KKK + k0 + 4]);
            wr[s][kt] = cvt8(*(const float4*)&Wr[n * KKK + k0],
                             *(const float4*)&Wr[n * KKK + k0 + 4]);
            wi[s][kt] = cvt8(*(const float4*)&Wi[n * KKK + k0],
                             *(const float4*)&Wi[n * KKK + k0 + 4]);
        }
    }
    float bzv[2], brv[2], biv[2];
    #pragma unroll
    for (int s = 0; s < 2; ++s) {
        const int n = 32 * w + 16 * s + ln;
        bzv[s] = bz[n]; brv[s] = br[n]; biv[s] = bi[n];
    }

    float h[2][4];
    #pragma unroll
    for (int s = 0; s < 2; ++s)
        #pragma unroll
        for (int i = 0; i < 4; ++i)
            h[s][i] = h0[(size_t)(b0 + 4 * q + i) * DLAT + 32 * w + 16 * s + ln];

    for (int idx = tid; idx < 16 * DLAT; idx += 256) {
        const int m = idx >> 7, c = idx & 127;
        const float v = h0[(size_t)(b0 + m) * DLAT + c];
        out[(size_t)(b0 + m) * DLAT + c] = v;
        hA[m][c] = (_Float16)v;
    }
    {
        const int m = tid >> 4, k4 = tid & 15;
        const float4 xv = *(const float4*)&seqs[((size_t)0 * BB + b0 + m) * DIN + k4 * 4];
        *(half4*)&xb[0][m][k4 * 4] =
            (half4){(_Float16)xv.x, (_Float16)xv.y, (_Float16)xv.z, (_Float16)xv.w};
    }
    __syncthreads();

    for (int t = 0; t < TT; ++t) {
        const int p = t & 1;
        float4 xv;
        const int xm = tid >> 4, xk = tid & 15;
        if (t + 1 < TT)
            xv = *(const float4*)&seqs[((size_t)(t + 1) * BB + b0 + xm) * DIN + xk * 4];

        half8 a0 = *(const half8*)&hA[ln][ 0 + q * 8];
        half8 a1 = *(const half8*)&hA[ln][32 + q * 8];
        half8 a2 = *(const half8*)&hA[ln][64 + q * 8];
        half8 a3 = *(const half8*)&hA[ln][96 + q * 8];
        half8 x0 = *(const half8*)&xb[p][ln][ 0 + q * 8];
        half8 x1 = *(const half8*)&xb[p][ln][32 + q * 8];

        f32x4 az[2], ar[2], ai[2];
        #pragma unroll
        for (int s = 0; s < 2; ++s) {
            az[s] = (f32x4){bzv[s], bzv[s], bzv[s], bzv[s]};
            ar[s] = (f32x4){brv[s], brv[s], brv[s], brv[s]};
            ai[s] = (f32x4){biv[s], biv[s], biv[s], biv[s]};
        }
        #pragma unroll
        for (int s = 0; s < 2; ++s) {
            az[s] = MFMA16(x0, wz[s][4], az[s]);
            az[s] = MFMA16(x1, wz[s][5], az[s]);
            ar[s] = MFMA16(x0, wr[s][4], ar[s]);
            ar[s] = MFMA16(x1, wr[s][5], ar[s]);
            ai[s] = MFMA16(x0, wi[s][4], ai[s]);
            ai[s] = MFMA16(x1, wi[s][5], ai[s]);
            az[s] = MFMA16(a0, wz[s][0], az[s]);
            az[s] = MFMA16(a1, wz[s][1], az[s]);
            az[s] = MFMA16(a2, wz[s][2], az[s]);
            az[s] = MFMA16(a3, wz[s][3], az[s]);
            ar[s] = MFMA16(a0, wr[s][0], ar[s]);
            ar[s] = MFMA16(a1, wr[s][1], ar[s]);
            ar[s] = MFMA16(a2, wr[s][2], ar[s]);
            ar[s] = MFMA16(a3, wr[s][3], ar[s]);
        }

        float zz[2][4];
        #pragma unroll
        for (int s = 0; s < 2; ++s)
            #pragma unroll
            for (int i = 0; i < 4; ++i) {
                zz[s][i]      = fsigmoid(az[s][i]);
                const float r = fsigmoid(ar[s][i]);
                hrA[4 * q + i][32 * w + 16 * s + ln] = (_Float16)(h[s][i] * r);
            }

        if (t + 1 < TT)
            *(half4*)&xb[p ^ 1][xm][xk * 4] =
                (half4){(_Float16)xv.x, (_Float16)xv.y, (_Float16)xv.z, (_Float16)xv.w};

        __syncthreads();

        half8 c0 = *(const half8*)&hrA[ln][ 0 + q * 8];
        half8 c1 = *(const half8*)&hrA[ln][32 + q * 8];
        half8 c2 = *(const half8*)&hrA[ln][64 + q * 8];
        half8 c3 = *(const half8*)&hrA[ln][96 + q * 8];
        #pragma unroll
        for (int s = 0; s < 2; ++s) {
            ai[s] = MFMA16(c0, wi[s][0], ai[s]);
            ai[s] = MFMA16(c1, wi[s][1], ai[s]);
            ai[s] = MFMA16(c2, wi[s][2], ai[s]);
            ai[s] = MFMA16(c3, wi[s][3], ai[s]);
        }

        #pragma unroll
        for (int s = 0; s < 2; ++s)
            #pragma unroll
            for (int i = 0; i < 4; ++i) {
                const float cand = ftanh(ai[s][i]);
                const float hn   = h[s][i] + zz[s][i] * (cand - h[s][i]);
                h[s][i] = hn;
                const int m = 4 * q + i, c = 32 * w + 16 * s + ln;
                hA[m][c] = (_Float16)hn;
                out[((size_t)(t + 1) * BB + b0 + m) * DLAT + c] = hn;
            }

        __syncthreads();
    }
}

extern "C" void kernel_launch(void* const* d_in, const int* in_sizes, int n_in,
                              void* d_out, int out_size, void* d_ws, size_t ws_size,
                              hipStream_t stream) {
    const float* seqs = (const float*)d_in[0];
    const float* h0   = (const float*)d_in[1];
    const float* Wz   = (const float*)d_in[2];
    const float* bz   = (const float*)d_in[3];
    const float* Wr   = (const float*)d_in[4];
    const float* br   = (const float*)d_in[5];
    const float* Wi   = (const float*)d_in[6];
    const float* bi   = (const float*)d_in[7];
    float* out = (float*)d_out;

    if (ws_size >= X_BYTES) {
        _Float16* X = (_Float16*)d_ws;
        xproj<<<(TT / TCHUNK) * NBLK, 256, 0, stream>>>(seqs, Wz, bz, Wr, br, Wi, bi, X);
        gru_rx<<<NBLK, 512, 0, stream>>>(h0, Wz, Wr, Wi, X, out);
    } else {
        gru_mfma<<<NBLK, 256, 0, stream>>>(seqs, h0, bz, br, bi, Wz, Wr, Wi, out);
    }
}